// Round 7
// baseline (127.465 us; speedup 1.0000x reference)
//
#include <hip/hip_runtime.h>

// Problem constants (from reference setup_inputs): B=4, N=M=4096, P=2048.
#define BB 4
#define NN 4096
#define PP 2048
#define CSPLIT 1024     // candidates per wave (4 waves cover all 4096)

// ws layout (floats):
//   [0..1023]  : per-block partial sums (grid = 960)
//   [4096.. ]  : float4 augmented arrays, a4 = (float4*)(ws + 4096):
#define RAWFULL 0        // (x,y,z,|c|^2) of full       -> candidates A
#define RAWPRED 16384    // (x,y,z,|c|^2) of pred       -> candidates B, C
#define RAWREFL 32768    // (x,y,z,|c|^2) of refl(pred) -> candidates D
#define SQPRED  49152    // (-2x,-2y,-2z,|q|^2) of pred    -> queries A, D
#define SQFULL  65536    // (-2x,-2y,-2z,|q|^2) of full    -> queries B
#define SQPART  81920    // (-2x,-2y,-2z,|q|^2) of partial -> queries C
// total 90112 float4 = 1.44 MB + results; d_ws is far larger.

__global__ __launch_bounds__(256) void prep_kernel(
    const float* __restrict__ pred, const float* __restrict__ full,
    const float* __restrict__ partial, const float* __restrict__ plane_n,
    const float* __restrict__ plane_off, float4* __restrict__ a4)
{
    int i = blockIdx.x * 256 + threadIdx.x;   // 0..16383
    int b = i >> 12, j = i & 4095;
    // full
    const float* f = full + (size_t)i * 3;
    float x = f[0], y = f[1], z = f[2];
    float s2 = fmaf(x, x, fmaf(y, y, z * z));
    a4[RAWFULL + i] = make_float4(x, y, z, s2);
    a4[SQFULL + i]  = make_float4(-2.f * x, -2.f * y, -2.f * z, s2);
    // pred
    const float* p = pred + (size_t)i * 3;
    float px = p[0], py = p[1], pz = p[2];
    float p2 = fmaf(px, px, fmaf(py, py, pz * pz));
    a4[RAWPRED + i] = make_float4(px, py, pz, p2);
    a4[SQPRED + i]  = make_float4(-2.f * px, -2.f * py, -2.f * pz, p2);
    // reflected pred (reflection baked in once)
    float nx = plane_n[b * 3], ny = plane_n[b * 3 + 1], nz = plane_n[b * 3 + 2];
    float off = plane_off[b];
    float sd = fmaf(px, nx, fmaf(py, ny, fmaf(pz, nz, off)));
    float rx = px - 2.f * sd * nx, ry = py - 2.f * sd * ny, rz = pz - 2.f * sd * nz;
    float r2 = fmaf(rx, rx, fmaf(ry, ry, rz * rz));
    a4[RAWREFL + i] = make_float4(rx, ry, rz, r2);
    // partial
    if (j < PP) {
        int pi = b * PP + j;
        const float* q = partial + (size_t)pi * 3;
        float qx = q[0], qy = q[1], qz = q[2];
        float q2 = fmaf(qx, qx, fmaf(qy, qy, qz * qz));
        a4[SQPART + pi] = make_float4(-2.f * qx, -2.f * qy, -2.f * qz, q2);
    }
}

// Block map (grid = 960, 256 threads):
//    0..255 : task A pred->full      (4 b x 64 chunks of 64 queries)
//  256..511 : task B full->pred
//  512..639 : task C partial->pred   (4 b x 32 chunks)
//  640..895 : task D pred->refl(pred)  (symmetric matrix -> one dir x2)
//  896..959 : task E normal consistency (256 pts/block)
// Each NN block: lane = one query (VGPR); wave wv streams candidates
// [wv*1024, wv*1024+1024) at wave-uniform addresses (SMEM s_load stream).
// Inner pair: t = c2 - 2 q.c via 1 mov + 3 fma, min3-combined. No LDS/DS
// in the main loop; per-query min is lane-local.

__global__ __launch_bounds__(256) void nn_kernel(
    const float4* __restrict__ a4,
    const float* __restrict__ pn, const float* __restrict__ gn,
    float* __restrict__ res)
{
    int blk = blockIdx.x;
    int tid = threadIdx.x;
    __shared__ float wmin[4][64];
    __shared__ float sred[4];

    if (blk >= 896) {
        // ---- task E: normal consistency ----
        int i = (blk - 896) * 256 + tid;   // 0 .. B*N-1
        const float* p = pn + (size_t)i * 3;
        const float* g = gn + (size_t)i * 3;
        float px = p[0], py = p[1], pz = p[2];
        float gx = g[0], gy = g[1], gz = g[2];
        float num = fmaf(px, gx, fmaf(py, gy, pz * gz));
        float den = sqrtf(fmaf(px, px, fmaf(py, py, pz * pz))) *
                    sqrtf(fmaf(gx, gx, fmaf(gy, gy, gz * gz)));
        float v = 1.f - fabsf(num / fmaxf(den, 1e-8f));
        for (int o = 1; o < 64; o <<= 1) v += __shfl_xor(v, o);
        if ((tid & 63) == 0) sred[tid >> 6] = v;
        __syncthreads();
        if (tid == 0) res[blk] = sred[0] + sred[1] + sred[2] + sred[3];
        return;
    }

    // ---- NN tasks ----
    int qoff, coff;
    if (blk < 256) {                 // A: pred -> full
        int b = blk >> 6; qoff = SQPRED + b * 4096 + (blk & 63) * 64;
        coff = RAWFULL + b * 4096;
    } else if (blk < 512) {          // B: full -> pred
        int t = blk - 256; int b = t >> 6;
        qoff = SQFULL + b * 4096 + (t & 63) * 64;
        coff = RAWPRED + b * 4096;
    } else if (blk < 640) {          // C: partial -> pred
        int t = blk - 512; int b = t >> 5;
        qoff = SQPART + b * 2048 + (t & 31) * 64;
        coff = RAWPRED + b * 4096;
    } else {                         // D: pred -> refl(pred)
        int t = blk - 640; int b = t >> 6;
        qoff = SQPRED + b * 4096 + (t & 63) * 64;
        coff = RAWREFL + b * 4096;
    }

    int lane = tid & 63;
    int wv = __builtin_amdgcn_readfirstlane(tid >> 6);   // force wave-uniform

    float4 q = a4[qoff + lane];                 // (-2qx,-2qy,-2qz,|q|^2)
    const float4* __restrict__ cp = a4 + coff + wv * CSPLIT;  // uniform addr

    float md = 3.4e38f;
#pragma unroll 8
    for (int k = 0; k < CSPLIT; k += 2) {
        float4 ca = cp[k];
        float4 cb = cp[k + 1];
        float ta = fmaf(ca.x, q.x, fmaf(ca.y, q.y, fmaf(ca.z, q.z, ca.w)));
        float tb = fmaf(cb.x, q.x, fmaf(cb.y, q.y, fmaf(cb.z, q.z, cb.w)));
        md = fminf(md, fminf(ta, tb));          // -> v_min3_f32
    }
    wmin[wv][lane] = md;
    __syncthreads();

    if (tid < 64) {
        float m = fminf(fminf(wmin[0][tid], wmin[1][tid]),
                        fminf(wmin[2][tid], wmin[3][tid]));
        float d = sqrtf(fmaxf(q.w + m, 0.f));   // wave-0 lane holds its own q2
        for (int o = 1; o < 64; o <<= 1) d += __shfl_xor(d, o);
        if (tid == 0) res[blk] = d;
    }
}

__global__ __launch_bounds__(256) void final_kernel(
    const float* __restrict__ res,
    const float* __restrict__ confs,
    const float* __restrict__ diff,
    float* __restrict__ out)
{
    __shared__ float seg[8];
    int tid = threadIdx.x;
    if (tid < 8) seg[tid] = 0.f;
    __syncthreads();
    for (int i = tid; i < 960; i += 256) {
        float v = res[i];
        int sgi;
        if (i < 256) sgi = 0;
        else if (i < 512) sgi = 1;
        else if (i < 640) sgi = 2;
        else if (i < 896) sgi = 3 + ((i - 640) >> 6);
        else sgi = 7;
        atomicAdd(&seg[sgi], v);
    }
    __syncthreads();
    if (tid == 0) {
        const float BN = (float)(BB * NN);
        const float BP = (float)(BB * PP);
        float cd  = seg[0] / BN + seg[1] / BN;
        float fid = seg[2] / BP;
        float nc  = seg[7] / BN;
        float sym = 0.f;
#pragma unroll
        for (int b = 0; b < BB; ++b) {
            float conf = confs[b];
            if (conf >= 0.25f) {
                // symmetric distance matrix -> both chamfer directions equal
                float cdl1 = 2.0f * seg[3 + b] / (float)NN;
                sym += conf * cdl1 * 0.5f;
            }
        }
        sym *= (1.0f / BB);
        out[0] = 1.0f * cd + 0.5f * fid + 0.1f * nc + 0.1f * sym + diff[0];
    }
}

extern "C" void kernel_launch(void* const* d_in, const int* in_sizes, int n_in,
                              void* d_out, int out_size, void* d_ws, size_t ws_size,
                              hipStream_t stream) {
    const float* pred      = (const float*)d_in[0];
    const float* full      = (const float*)d_in[1];
    const float* partial   = (const float*)d_in[2];
    // d_in[3]=mu, d_in[4]=logvar: KL term has coefficient 0 -> unused
    const float* pred_n    = (const float*)d_in[5];
    const float* gt_n      = (const float*)d_in[6];
    const float* plane_n   = (const float*)d_in[7];
    const float* plane_off = (const float*)d_in[8];
    const float* confs     = (const float*)d_in[9];
    const float* diff      = (const float*)d_in[10];
    float* ws = (float*)d_ws;
    float4* a4 = (float4*)(ws + 4096);

    prep_kernel<<<64, 256, 0, stream>>>(pred, full, partial, plane_n,
                                        plane_off, a4);
    nn_kernel<<<960, 256, 0, stream>>>(a4, pred_n, gt_n, ws);
    final_kernel<<<1, 256, 0, stream>>>(ws, confs, diff, (float*)d_out);
}

// Round 8
// 51.275 us; speedup vs baseline: 2.4859x; 2.4859x over previous
//
#include <hip/hip_runtime.h>

// Problem constants (from reference setup_inputs): B=4, N=M=4096, P=2048.
#define BB 4
#define NN 4096
#define PP 2048
#define QW 16            // queries per wave (held in SGPRs)

// ws layout (floats):
//   [0..3647]  : per-wave-group partial sums (res)
//   [4096.. ]  : float4 augmented arrays, a4 = (float4*)(ws + 4096):
#define RAWFULL 0        // (x,y,z,|c|^2) of full       -> candidates A
#define RAWPRED 16384    // (x,y,z,|c|^2) of pred       -> candidates B, C
#define RAWREFL 32768    // (x,y,z,|c|^2) of refl(pred) -> candidates D
#define SQPRED  49152    // (-2x,-2y,-2z,|q|^2) of pred    -> queries A, D
#define SQFULL  65536    // (-2x,-2y,-2z,|q|^2) of full    -> queries B
#define SQPART  81920    // (-2x,-2y,-2z,|q|^2) of partial -> queries C

__global__ __launch_bounds__(256) void prep_kernel(
    const float* __restrict__ pred, const float* __restrict__ full,
    const float* __restrict__ partial, const float* __restrict__ plane_n,
    const float* __restrict__ plane_off, float4* __restrict__ a4)
{
    int i = blockIdx.x * 256 + threadIdx.x;   // 0..16383
    int b = i >> 12, j = i & 4095;
    // full
    const float* f = full + (size_t)i * 3;
    float x = f[0], y = f[1], z = f[2];
    float s2 = fmaf(x, x, fmaf(y, y, z * z));
    a4[RAWFULL + i] = make_float4(x, y, z, s2);
    a4[SQFULL + i]  = make_float4(-2.f * x, -2.f * y, -2.f * z, s2);
    // pred
    const float* p = pred + (size_t)i * 3;
    float px = p[0], py = p[1], pz = p[2];
    float p2 = fmaf(px, px, fmaf(py, py, pz * pz));
    a4[RAWPRED + i] = make_float4(px, py, pz, p2);
    a4[SQPRED + i]  = make_float4(-2.f * px, -2.f * py, -2.f * pz, p2);
    // reflected pred (reflection baked in once)
    float nx = plane_n[b * 3], ny = plane_n[b * 3 + 1], nz = plane_n[b * 3 + 2];
    float off = plane_off[b];
    float sd = fmaf(px, nx, fmaf(py, ny, fmaf(pz, nz, off)));
    float rx = px - 2.f * sd * nx, ry = py - 2.f * sd * ny, rz = pz - 2.f * sd * nz;
    float r2 = fmaf(rx, rx, fmaf(ry, ry, rz * rz));
    a4[RAWREFL + i] = make_float4(rx, ry, rz, r2);
    // partial
    if (j < PP) {
        int pi = b * PP + j;
        const float* q = partial + (size_t)pi * 3;
        float qx = q[0], qy = q[1], qz = q[2];
        float q2 = fmaf(qx, qx, fmaf(qy, qy, qz * qz));
        a4[SQPART + pi] = make_float4(-2.f * qx, -2.f * qy, -2.f * qz, q2);
    }
}

// Block map (grid = 960, 256 threads = 4 waves):
//    0..255 : task A  (b = blk>>6)         cand RAWFULL, queries SQPRED
//  256..639 : task B+C (t=blk-256, b=t/96) cand RAWPRED, queries SQFULL/SQPART
//  640..895 : task D  (b = (blk-640)>>6)   cand RAWREFL, queries SQPRED
//  896..959 : task E normal consistency (256 pts/block)
// Each block stages its 4096-candidate array into LDS once (1 barrier);
// each wave then serves QW=16 wave-uniform queries (SGPR) against all of
// LDS: 3 fma + shared min3 per pair, lane-local min, shuffle-reduce epilogue.
// res slots: A 0..1023 | B 1024..2047 | C 2048..2559 | D 2560+b*256+g | NC 3584+.

__global__ __launch_bounds__(256) void nn_kernel(
    const float4* __restrict__ a4,
    const float* __restrict__ pn, const float* __restrict__ gn,
    float* __restrict__ res)
{
    int blk = blockIdx.x;
    int tid = threadIdx.x;
    __shared__ float4 sc[4096];

    if (blk >= 896) {
        // ---- task E: normal consistency ----
        float* sred = (float*)sc;
        int i = (blk - 896) * 256 + tid;   // 0 .. B*N-1
        const float* p = pn + (size_t)i * 3;
        const float* g = gn + (size_t)i * 3;
        float px = p[0], py = p[1], pz = p[2];
        float gx = g[0], gy = g[1], gz = g[2];
        float num = fmaf(px, gx, fmaf(py, gy, pz * gz));
        float den = sqrtf(fmaf(px, px, fmaf(py, py, pz * pz))) *
                    sqrtf(fmaf(gx, gx, fmaf(gy, gy, gz * gz)));
        float v = 1.f - fabsf(num / fmaxf(den, 1e-8f));
        for (int o = 1; o < 64; o <<= 1) v += __shfl_xor(v, o);
        if ((tid & 63) == 0) sred[tid >> 6] = v;
        __syncthreads();
        if (tid == 0) res[3584 + (blk - 896)] = sred[0] + sred[1] + sred[2] + sred[3];
        return;
    }

    int lane = tid & 63;
    int wv = __builtin_amdgcn_readfirstlane(tid >> 6);

    // ---- task decode ----
    int coff, qbase, slot;
    if (blk < 256) {                          // A: pred -> full
        int b = blk >> 6, gg = (blk & 63) * 4 + wv;
        coff = RAWFULL + b * 4096;
        qbase = SQPRED + b * 4096 + gg * QW;
        slot = b * 256 + gg;
    } else if (blk < 640) {                   // B: full->pred, C: partial->pred
        int t = blk - 256, b = t / 96, r = t % 96;
        int gg = r * 4 + wv;                  // 0..383
        coff = RAWPRED + b * 4096;
        if (gg < 256) {                       // B
            qbase = SQFULL + b * 4096 + gg * QW;
            slot = 1024 + b * 256 + gg;
        } else {                              // C
            int qq = gg - 256;                // 0..127
            qbase = SQPART + b * 2048 + qq * QW;
            slot = 2048 + b * 128 + qq;
        }
    } else {                                  // D: pred -> refl(pred)
        int t = blk - 640, b = t >> 6, gg = (t & 63) * 4 + wv;
        coff = RAWREFL + b * 4096;
        qbase = SQPRED + b * 4096 + gg * QW;
        slot = 2560 + b * 256 + gg;
    }
    qbase = __builtin_amdgcn_readfirstlane(qbase);

    // ---- stage all 4096 candidates into LDS (once) ----
    const float4* __restrict__ cand = a4 + coff;
#pragma unroll
    for (int r = 0; r < 16; ++r)
        sc[r * 256 + tid] = cand[r * 256 + tid];
    __syncthreads();

    // ---- wave-uniform queries -> SGPRs ----
    float4 q[QW];
#pragma unroll
    for (int j = 0; j < QW; ++j) q[j] = a4[qbase + j];

    float md[QW];
#pragma unroll
    for (int j = 0; j < QW; ++j) md[j] = 3.4e38f;

    // ---- main loop: 4 candidates/lane/iter, no barriers ----
#pragma unroll 2
    for (int k = 0; k < 4096; k += 256) {
        float4 ca = sc[k + lane];
        float4 cb = sc[k + 64 + lane];
        float4 cc = sc[k + 128 + lane];
        float4 cd = sc[k + 192 + lane];
#pragma unroll
        for (int j = 0; j < QW; ++j) {
            float ta = fmaf(ca.x, q[j].x, fmaf(ca.y, q[j].y, fmaf(ca.z, q[j].z, ca.w)));
            float tb = fmaf(cb.x, q[j].x, fmaf(cb.y, q[j].y, fmaf(cb.z, q[j].z, cb.w)));
            float tc = fmaf(cc.x, q[j].x, fmaf(cc.y, q[j].y, fmaf(cc.z, q[j].z, cc.w)));
            float td = fmaf(cd.x, q[j].x, fmaf(cd.y, q[j].y, fmaf(cd.z, q[j].z, cd.w)));
            md[j] = fminf(md[j], fminf(ta, tb));   // v_min3
            md[j] = fminf(md[j], fminf(tc, td));   // v_min3
        }
    }

    // ---- cross-lane min per query, then sum of sqrt on lane 0 ----
#pragma unroll
    for (int j = 0; j < QW; ++j) {
        md[j] = fminf(md[j], __shfl_xor(md[j], 1));
        md[j] = fminf(md[j], __shfl_xor(md[j], 2));
        md[j] = fminf(md[j], __shfl_xor(md[j], 4));
        md[j] = fminf(md[j], __shfl_xor(md[j], 8));
        md[j] = fminf(md[j], __shfl_xor(md[j], 16));
        md[j] = fminf(md[j], __shfl_xor(md[j], 32));
    }
    if (lane == 0) {
        float s = 0.f;
#pragma unroll
        for (int j = 0; j < QW; ++j)
            s += sqrtf(fmaxf(q[j].w + md[j], 0.f));
        res[slot] = s;
    }
}

__global__ __launch_bounds__(256) void final_kernel(
    const float* __restrict__ res,
    const float* __restrict__ confs,
    const float* __restrict__ diff,
    float* __restrict__ out)
{
    __shared__ float seg[8];
    int tid = threadIdx.x;
    if (tid < 8) seg[tid] = 0.f;
    __syncthreads();
    for (int i = tid; i < 3648; i += 256) {
        float v = res[i];
        int sgi;
        if (i < 1024) sgi = 0;
        else if (i < 2048) sgi = 1;
        else if (i < 2560) sgi = 2;
        else if (i < 3584) sgi = 3 + ((i - 2560) >> 8);
        else sgi = 7;
        atomicAdd(&seg[sgi], v);
    }
    __syncthreads();
    if (tid == 0) {
        const float BN = (float)(BB * NN);
        const float BP = (float)(BB * PP);
        float cd  = seg[0] / BN + seg[1] / BN;
        float fid = seg[2] / BP;
        float nc  = seg[7] / BN;
        float sym = 0.f;
#pragma unroll
        for (int b = 0; b < BB; ++b) {
            float conf = confs[b];
            if (conf >= 0.25f) {
                // symmetric distance matrix -> both chamfer directions equal
                float cdl1 = 2.0f * seg[3 + b] / (float)NN;
                sym += conf * cdl1 * 0.5f;
            }
        }
        sym *= (1.0f / BB);
        out[0] = 1.0f * cd + 0.5f * fid + 0.1f * nc + 0.1f * sym + diff[0];
    }
}

extern "C" void kernel_launch(void* const* d_in, const int* in_sizes, int n_in,
                              void* d_out, int out_size, void* d_ws, size_t ws_size,
                              hipStream_t stream) {
    const float* pred      = (const float*)d_in[0];
    const float* full      = (const float*)d_in[1];
    const float* partial   = (const float*)d_in[2];
    // d_in[3]=mu, d_in[4]=logvar: KL term has coefficient 0 -> unused
    const float* pred_n    = (const float*)d_in[5];
    const float* gt_n      = (const float*)d_in[6];
    const float* plane_n   = (const float*)d_in[7];
    const float* plane_off = (const float*)d_in[8];
    const float* confs     = (const float*)d_in[9];
    const float* diff      = (const float*)d_in[10];
    float* ws = (float*)d_ws;
    float4* a4 = (float4*)(ws + 4096);

    prep_kernel<<<64, 256, 0, stream>>>(pred, full, partial, plane_n,
                                        plane_off, a4);
    nn_kernel<<<960, 256, 0, stream>>>(a4, pred_n, gt_n, ws);
    final_kernel<<<1, 256, 0, stream>>>(ws, confs, diff, (float*)d_out);
}

// Round 9
// 44.819 us; speedup vs baseline: 2.8440x; 1.1441x over previous
//
#include <hip/hip_runtime.h>

// Problem constants (from reference setup_inputs): B=4, N=M=4096, P=2048.
#define BB 4
#define NN 4096
#define PP 2048

#define TILE 512       // candidates per LDS tile
#define NTILE 8        // 4096 / TILE
#define QPT 16         // queries per wave (SGPR-resident, wave-uniform)
#define QPB 64         // queries per block = 4 waves * QPT

// ws layout (floats):
//   [0..959]   : per-block partial sums (res)
//   [4096.. ]  : float4 augmented arrays, a4 = (float4*)(ws + 4096):
#define RAWFULL 0        // (x,y,z,|c|^2) of full       -> candidates A
#define RAWPRED 16384    // (x,y,z,|c|^2) of pred       -> candidates B, C
#define RAWREFL 32768    // (x,y,z,|c|^2) of refl(pred) -> candidates D
#define SQPRED  49152    // (-2x,-2y,-2z,|q|^2) of pred    -> queries A, D
#define SQFULL  65536    // (-2x,-2y,-2z,|q|^2) of full    -> queries B
#define SQPART  81920    // (-2x,-2y,-2z,|q|^2) of partial -> queries C

__global__ __launch_bounds__(256) void prep_kernel(
    const float* __restrict__ pred, const float* __restrict__ full,
    const float* __restrict__ partial, const float* __restrict__ plane_n,
    const float* __restrict__ plane_off, float4* __restrict__ a4)
{
    int i = blockIdx.x * 256 + threadIdx.x;   // 0..16383
    int b = i >> 12, j = i & 4095;
    // full
    const float* f = full + (size_t)i * 3;
    float x = f[0], y = f[1], z = f[2];
    float s2 = fmaf(x, x, fmaf(y, y, z * z));
    a4[RAWFULL + i] = make_float4(x, y, z, s2);
    a4[SQFULL + i]  = make_float4(-2.f * x, -2.f * y, -2.f * z, s2);
    // pred
    const float* p = pred + (size_t)i * 3;
    float px = p[0], py = p[1], pz = p[2];
    float p2 = fmaf(px, px, fmaf(py, py, pz * pz));
    a4[RAWPRED + i] = make_float4(px, py, pz, p2);
    a4[SQPRED + i]  = make_float4(-2.f * px, -2.f * py, -2.f * pz, p2);
    // reflected pred (reflection baked in once)
    float nx = plane_n[b * 3], ny = plane_n[b * 3 + 1], nz = plane_n[b * 3 + 2];
    float off = plane_off[b];
    float sd = fmaf(px, nx, fmaf(py, ny, fmaf(pz, nz, off)));
    float rx = px - 2.f * sd * nx, ry = py - 2.f * sd * ny, rz = pz - 2.f * sd * nz;
    float r2 = fmaf(rx, rx, fmaf(ry, ry, rz * rz));
    a4[RAWREFL + i] = make_float4(rx, ry, rz, r2);
    // partial
    if (j < PP) {
        int pi = b * PP + j;
        const float* q = partial + (size_t)pi * 3;
        float qx = q[0], qy = q[1], qz = q[2];
        float q2 = fmaf(qx, qx, fmaf(qy, qy, qz * qz));
        a4[SQPART + pi] = make_float4(-2.f * qx, -2.f * qy, -2.f * qz, q2);
    }
}

// Block map (grid = 960, 256 threads = 4 waves):
//    0..255 : task A pred->full   (b=blk>>6, chunk=blk&63)
//  256..511 : task B full->pred
//  512..639 : task C partial->pred (b=t>>5, chunk=t&31)
//  640..895 : task D pred->refl(pred) (symmetric matrix -> one dir x2)
//  896..959 : task E normal consistency (256 pts/block)
// R3-proven skeleton: 8 x 512-candidate LDS tiles, double-buffered,
// reg-prefetch, 2 barriers/tile. New: candidates arrive prepped as
// (x,y,z,|c|^2) float4 (pure-copy staging, reflection pre-baked); each
// wave's 16 queries are wave-uniform float4 (-2q,|q|^2) in SGPRs.
// Inner pair: 3 v_fma(vgpr,sgpr,vgpr) + 1/2 v_min3 = 3.5 VALU.

__global__ __launch_bounds__(256, 4) void nn_kernel(
    const float4* __restrict__ a4,
    const float* __restrict__ pn, const float* __restrict__ gn,
    float* __restrict__ res)
{
    int blk = blockIdx.x;
    int tid = threadIdx.x;
    __shared__ float4 sc[2][TILE];
    __shared__ float sred[4];

    if (blk >= 896) {
        // ---- task E: normal consistency ----
        int i = (blk - 896) * 256 + tid;   // 0 .. B*N-1
        const float* p = pn + (size_t)i * 3;
        const float* g = gn + (size_t)i * 3;
        float px = p[0], py = p[1], pz = p[2];
        float gx = g[0], gy = g[1], gz = g[2];
        float num = fmaf(px, gx, fmaf(py, gy, pz * gz));
        float den = sqrtf(fmaf(px, px, fmaf(py, py, pz * pz))) *
                    sqrtf(fmaf(gx, gx, fmaf(gy, gy, gz * gz)));
        float v = 1.f - fabsf(num / fmaxf(den, 1e-8f));
        for (int o = 1; o < 64; o <<= 1) v += __shfl_xor(v, o);
        if ((tid & 63) == 0) sred[tid >> 6] = v;
        __syncthreads();
        if (tid == 0) res[blk] = sred[0] + sred[1] + sred[2] + sred[3];
        return;
    }

    // ---- NN task decode ----
    int coff, qbase;
    if (blk < 256) {                          // A: pred -> full
        int b = blk >> 6;
        coff = RAWFULL + b * 4096;
        qbase = SQPRED + b * 4096 + (blk & 63) * QPB;
    } else if (blk < 512) {                   // B: full -> pred
        int t = blk - 256, b = t >> 6;
        coff = RAWPRED + b * 4096;
        qbase = SQFULL + b * 4096 + (t & 63) * QPB;
    } else if (blk < 640) {                   // C: partial -> pred
        int t = blk - 512, b = t >> 5;
        coff = RAWPRED + b * 4096;
        qbase = SQPART + b * 2048 + (t & 31) * QPB;
    } else {                                  // D: pred -> refl(pred)
        int t = blk - 640, b = t >> 6;
        coff = RAWREFL + b * 4096;
        qbase = SQPRED + b * 4096 + (t & 63) * QPB;
    }

    int lane = tid & 63;
    int wv = __builtin_amdgcn_readfirstlane(tid >> 6);
    const float4* __restrict__ cand = a4 + coff;

    // ---- wave-uniform queries -> SGPRs ----
    int qo = __builtin_amdgcn_readfirstlane(qbase + wv * QPT);
    float4 q[QPT];
#pragma unroll
    for (int j = 0; j < QPT; ++j) q[j] = a4[qo + j];

    float md[QPT];
#pragma unroll
    for (int j = 0; j < QPT; ++j) md[j] = 3.4e38f;

    float4 r0, r1;
#define LOADT(TB) do { r0 = cand[(TB) + tid]; r1 = cand[(TB) + tid + 256]; } while (0)
#define WRITET(BUF) do { (BUF)[tid] = r0; (BUF)[tid + 256] = r1; } while (0)

    // prologue: stage tile 0
    LOADT(0);
    WRITET(sc[0]);
    __syncthreads();

    for (int t = 0; t < NTILE; ++t) {
        int cur = t & 1;
        if (t + 1 < NTILE) LOADT((t + 1) * TILE);   // prefetch to regs
        const float4* s = sc[cur];
#pragma unroll
        for (int k = 0; k < TILE / 64; k += 2) {
            float4 ca = s[lane + k * 64];
            float4 cb = s[lane + (k + 1) * 64];
#pragma unroll
            for (int j = 0; j < QPT; ++j) {
                float ta = fmaf(ca.x, q[j].x, fmaf(ca.y, q[j].y, fmaf(ca.z, q[j].z, ca.w)));
                float tb = fmaf(cb.x, q[j].x, fmaf(cb.y, q[j].y, fmaf(cb.z, q[j].z, cb.w)));
                md[j] = fminf(md[j], fminf(ta, tb));   // v_min3_f32
            }
        }
        __syncthreads();
        if (t + 1 < NTILE) {
            WRITET(sc[cur ^ 1]);
            __syncthreads();
        }
    }

    // ---- cross-lane min per query, then sum of sqrt on lane 0 ----
#pragma unroll
    for (int j = 0; j < QPT; ++j) {
        md[j] = fminf(md[j], __shfl_xor(md[j], 1));
        md[j] = fminf(md[j], __shfl_xor(md[j], 2));
        md[j] = fminf(md[j], __shfl_xor(md[j], 4));
        md[j] = fminf(md[j], __shfl_xor(md[j], 8));
        md[j] = fminf(md[j], __shfl_xor(md[j], 16));
        md[j] = fminf(md[j], __shfl_xor(md[j], 32));
    }
    if (lane == 0) {
        float s = 0.f;
#pragma unroll
        for (int j = 0; j < QPT; ++j)
            s += sqrtf(fmaxf(q[j].w + md[j], 0.f));
        sred[wv] = s;
    }
    __syncthreads();
    if (tid == 0)
        res[blk] = sred[0] + sred[1] + sred[2] + sred[3];
}

__global__ __launch_bounds__(256) void final_kernel(
    const float* __restrict__ res,
    const float* __restrict__ confs,
    const float* __restrict__ diff,
    float* __restrict__ out)
{
    __shared__ float seg[8];
    int tid = threadIdx.x;
    if (tid < 8) seg[tid] = 0.f;
    __syncthreads();
    for (int i = tid; i < 960; i += 256) {
        float v = res[i];
        int sgi;
        if (i < 256) sgi = 0;
        else if (i < 512) sgi = 1;
        else if (i < 640) sgi = 2;
        else if (i < 896) sgi = 3 + ((i - 640) >> 6);
        else sgi = 7;
        atomicAdd(&seg[sgi], v);
    }
    __syncthreads();
    if (tid == 0) {
        const float BN = (float)(BB * NN);
        const float BP = (float)(BB * PP);
        float cd  = seg[0] / BN + seg[1] / BN;
        float fid = seg[2] / BP;
        float nc  = seg[7] / BN;
        float sym = 0.f;
#pragma unroll
        for (int b = 0; b < BB; ++b) {
            float conf = confs[b];
            if (conf >= 0.25f) {
                // symmetric distance matrix -> both chamfer directions equal
                float cdl1 = 2.0f * seg[3 + b] / (float)NN;
                sym += conf * cdl1 * 0.5f;
            }
        }
        sym *= (1.0f / BB);
        out[0] = 1.0f * cd + 0.5f * fid + 0.1f * nc + 0.1f * sym + diff[0];
    }
}

extern "C" void kernel_launch(void* const* d_in, const int* in_sizes, int n_in,
                              void* d_out, int out_size, void* d_ws, size_t ws_size,
                              hipStream_t stream) {
    const float* pred      = (const float*)d_in[0];
    const float* full      = (const float*)d_in[1];
    const float* partial   = (const float*)d_in[2];
    // d_in[3]=mu, d_in[4]=logvar: KL term has coefficient 0 -> unused
    const float* pred_n    = (const float*)d_in[5];
    const float* gt_n      = (const float*)d_in[6];
    const float* plane_n   = (const float*)d_in[7];
    const float* plane_off = (const float*)d_in[8];
    const float* confs     = (const float*)d_in[9];
    const float* diff      = (const float*)d_in[10];
    float* ws = (float*)d_ws;
    float4* a4 = (float4*)(ws + 4096);

    prep_kernel<<<64, 256, 0, stream>>>(pred, full, partial, plane_n,
                                        plane_off, a4);
    nn_kernel<<<960, 256, 0, stream>>>(a4, pred_n, gt_n, ws);
    final_kernel<<<1, 256, 0, stream>>>(ws, confs, diff, (float*)d_out);
}

// Round 10
// 35.233 us; speedup vs baseline: 3.6178x; 1.2721x over previous
//
#include <hip/hip_runtime.h>

// Problem constants: B=4, N=M=4096, P=2048.
#define BB 4
#define NN 4096
#define PP 2048

#define HCAND 2048     // candidates per block (half of 4096)
#define QPT 8          // queries per wave (wave-shared, broadcast)
#define QPB 32         // queries per block = 4 waves * QPT

// Total queries: A 16384 | B 16384 | C 8192 | D 16384 = 57344.
// ws float layout:
//   [0 .. 114687]      md per (query, half): slot = qslot*2 + half
//   [114688 .. 114751] NC per-block partials (64)
//   [114752 .. 114975] pass2 per-block partials (224)
#define NCOFF 114688
#define P2OFF 114752

// nn grid = 3648: blocks 0..3583 NN (t=blk>>1, half=blk&1), 3584..3647 NC.
//   t:    0.. 511 A pred->full   (b=t>>7, ch=t&127)
//        512..1023 B full->pred
//       1024..1279 C partial->pred (b=u>>6, ch=u&63)
//       1280..1791 D pred->refl(pred)  (symmetric -> one direction x2)
// Each block: stage HCAND candidates (reflect/|c|^2 inline) into 32KB LDS,
// ONE barrier, then barrier-free inner loop; per-wave 8 broadcast queries;
// inner pair = 3 v_fma + 1/2 v_min3 = 3.5 VALU. Epilogue: shuffle-min,
// lane0 stores raw md (no sqrt) to ws for the cross-half merge in pass2.

__global__ __launch_bounds__(256, 4) void nn_kernel(
    const float* __restrict__ pred, const float* __restrict__ full,
    const float* __restrict__ partial, const float* __restrict__ plane_n,
    const float* __restrict__ plane_off,
    const float* __restrict__ pn, const float* __restrict__ gn,
    float* __restrict__ ws)
{
    int blk = blockIdx.x;
    int tid = threadIdx.x;
    __shared__ float4 sc[HCAND];
    __shared__ float sred[4];

    if (blk >= 3584) {
        // ---- NC: normal consistency ----
        int i = (blk - 3584) * 256 + tid;
        const float* p = pn + (size_t)i * 3;
        const float* g = gn + (size_t)i * 3;
        float px = p[0], py = p[1], pz = p[2];
        float gx = g[0], gy = g[1], gz = g[2];
        float num = fmaf(px, gx, fmaf(py, gy, pz * gz));
        float den = sqrtf(fmaf(px, px, fmaf(py, py, pz * pz))) *
                    sqrtf(fmaf(gx, gx, fmaf(gy, gy, gz * gz)));
        float v = 1.f - fabsf(num / fmaxf(den, 1e-8f));
        for (int o = 1; o < 64; o <<= 1) v += __shfl_xor(v, o);
        if ((tid & 63) == 0) sred[tid >> 6] = v;
        __syncthreads();
        if (tid == 0) ws[NCOFF + (blk - 3584)] = sred[0] + sred[1] + sred[2] + sred[3];
        return;
    }

    // ---- decode ----
    int half = blk & 1, t = blk >> 1;
    const float* cand; const float* qptr; int qsl; bool reflect = false; int b;
    if (t < 512) {                       // A: pred -> full
        b = t >> 7; int ch = t & 127;
        cand = full + (size_t)b * NN * 3;
        qptr = pred + ((size_t)b * NN + ch * QPB) * 3;
        qsl = b * 4096 + ch * QPB;
    } else if (t < 1024) {               // B: full -> pred
        int u = t - 512; b = u >> 7; int ch = u & 127;
        cand = pred + (size_t)b * NN * 3;
        qptr = full + ((size_t)b * NN + ch * QPB) * 3;
        qsl = 16384 + b * 4096 + ch * QPB;
    } else if (t < 1280) {               // C: partial -> pred
        int u = t - 1024; b = u >> 6; int ch = u & 63;
        cand = pred + (size_t)b * NN * 3;
        qptr = partial + ((size_t)b * PP + ch * QPB) * 3;
        qsl = 32768 + b * 2048 + ch * QPB;
    } else {                             // D: pred -> refl(pred)
        int u = t - 1280; b = u >> 7; int ch = u & 127;
        cand = pred + (size_t)b * NN * 3;
        qptr = pred + ((size_t)b * NN + ch * QPB) * 3;
        qsl = 40960 + b * 4096 + ch * QPB;
        reflect = true;
    }

    float nx = 0.f, ny = 0.f, nz = 0.f, noff = 0.f;
    if (reflect) {
        nx = plane_n[b * 3]; ny = plane_n[b * 3 + 1]; nz = plane_n[b * 3 + 2];
        noff = plane_off[b];
    }

    // ---- stage HCAND candidates once (reflect + |c|^2 inline) ----
    int cbase = half * HCAND;
#pragma unroll
    for (int r = 0; r < HCAND / 256; ++r) {
        const float* cp = cand + (size_t)(cbase + r * 256 + tid) * 3;
        float x = cp[0], y = cp[1], z = cp[2];
        if (reflect) {
            float sd = fmaf(x, nx, fmaf(y, ny, fmaf(z, nz, noff)));
            float t2 = 2.0f * sd;
            x -= t2 * nx; y -= t2 * ny; z -= t2 * nz;
        }
        sc[r * 256 + tid] = make_float4(x, y, z, fmaf(x, x, fmaf(y, y, z * z)));
    }
    __syncthreads();

    // ---- per-wave broadcast queries ----
    int lane = tid & 63;
    int wv = tid >> 6;
    float ax[QPT], ay[QPT], az[QPT], md[QPT];
#pragma unroll
    for (int j = 0; j < QPT; ++j) {
        const float* qp = qptr + (size_t)(wv * QPT + j) * 3;   // wave-uniform
        ax[j] = -2.f * qp[0]; ay[j] = -2.f * qp[1]; az[j] = -2.f * qp[2];
        md[j] = 3.4e38f;
    }

    // ---- barrier-free main loop: 2048 cands, 2 per lane-iter ----
#pragma unroll 4
    for (int k = 0; k < HCAND / 128; ++k) {
        float4 ca = sc[k * 128 + lane];
        float4 cb = sc[k * 128 + 64 + lane];
#pragma unroll
        for (int j = 0; j < QPT; ++j) {
            float ta = fmaf(ax[j], ca.x, fmaf(ay[j], ca.y, fmaf(az[j], ca.z, ca.w)));
            float tb = fmaf(ax[j], cb.x, fmaf(ay[j], cb.y, fmaf(az[j], cb.z, cb.w)));
            md[j] = fminf(md[j], fminf(ta, tb));   // v_min3_f32
        }
    }

    // ---- cross-lane min; lane0 stores raw md per (query, half) ----
#pragma unroll
    for (int j = 0; j < QPT; ++j) {
        md[j] = fminf(md[j], __shfl_xor(md[j], 1));
        md[j] = fminf(md[j], __shfl_xor(md[j], 2));
        md[j] = fminf(md[j], __shfl_xor(md[j], 4));
        md[j] = fminf(md[j], __shfl_xor(md[j], 8));
        md[j] = fminf(md[j], __shfl_xor(md[j], 16));
        md[j] = fminf(md[j], __shfl_xor(md[j], 32));
    }
    if (lane == 0) {
#pragma unroll
        for (int j = 0; j < QPT; ++j)
            ws[(size_t)(qsl + wv * QPT + j) * 2 + half] = md[j];
    }
}

// pass2: one thread per query (57344). Merge halves, add |q|^2, sqrt,
// deterministic block reduction -> per-block partial (blocks are seg-pure).
__global__ __launch_bounds__(256) void pass2_kernel(
    const float* __restrict__ pred, const float* __restrict__ full,
    const float* __restrict__ partial, float* __restrict__ ws)
{
    int i = blockIdx.x * 256 + threadIdx.x;   // 0..57343
    const float* q;
    if (i < 16384)       q = pred + (size_t)i * 3;
    else if (i < 32768)  q = full + (size_t)(i - 16384) * 3;
    else if (i < 40960)  q = partial + (size_t)(i - 32768) * 3;
    else                 q = pred + (size_t)(i - 40960) * 3;
    float m = fminf(ws[(size_t)i * 2], ws[(size_t)i * 2 + 1]);
    float x = q[0], y = q[1], z = q[2];
    float q2 = fmaf(x, x, fmaf(y, y, z * z));
    float d = sqrtf(fmaxf(q2 + m, 0.f));
    for (int o = 1; o < 64; o <<= 1) d += __shfl_xor(d, o);
    __shared__ float sred[4];
    int tid = threadIdx.x;
    if ((tid & 63) == 0) sred[tid >> 6] = d;
    __syncthreads();
    if (tid == 0)
        ws[P2OFF + blockIdx.x] = sred[0] + sred[1] + sred[2] + sred[3];
}

__global__ __launch_bounds__(256) void final_kernel(
    const float* __restrict__ ws,
    const float* __restrict__ confs,
    const float* __restrict__ diff,
    float* __restrict__ out)
{
    __shared__ float vals[224 + 64];
    int tid = threadIdx.x;
    if (tid < 224) vals[tid] = ws[P2OFF + tid];
    if (tid < 64) vals[224 + tid] = ws[NCOFF + tid];
    __syncthreads();
    if (tid == 0) {
        float seg[8];
        for (int s = 0; s < 8; ++s) seg[s] = 0.f;
        for (int i = 0; i < 64; ++i)  seg[0] += vals[i];          // A
        for (int i = 64; i < 128; ++i) seg[1] += vals[i];         // B
        for (int i = 128; i < 160; ++i) seg[2] += vals[i];        // C
        for (int i = 160; i < 224; ++i) seg[3 + ((i - 160) >> 4)] += vals[i];  // D per batch
        for (int i = 0; i < 64; ++i)  seg[7] += vals[224 + i];    // NC
        const float BN = (float)(BB * NN);
        const float BP = (float)(BB * PP);
        float cd  = seg[0] / BN + seg[1] / BN;
        float fid = seg[2] / BP;
        float nc  = seg[7] / BN;
        float sym = 0.f;
#pragma unroll
        for (int b = 0; b < BB; ++b) {
            float conf = confs[b];
            if (conf >= 0.25f) {
                // symmetric distance matrix -> both chamfer directions equal
                float cdl1 = 2.0f * seg[3 + b] / (float)NN;
                sym += conf * cdl1 * 0.5f;
            }
        }
        sym *= (1.0f / BB);
        out[0] = 1.0f * cd + 0.5f * fid + 0.1f * nc + 0.1f * sym + diff[0];
    }
}

extern "C" void kernel_launch(void* const* d_in, const int* in_sizes, int n_in,
                              void* d_out, int out_size, void* d_ws, size_t ws_size,
                              hipStream_t stream) {
    const float* pred      = (const float*)d_in[0];
    const float* full      = (const float*)d_in[1];
    const float* partial   = (const float*)d_in[2];
    // d_in[3]=mu, d_in[4]=logvar: KL term has coefficient 0 -> unused
    const float* pred_n    = (const float*)d_in[5];
    const float* gt_n      = (const float*)d_in[6];
    const float* plane_n   = (const float*)d_in[7];
    const float* plane_off = (const float*)d_in[8];
    const float* confs     = (const float*)d_in[9];
    const float* diff      = (const float*)d_in[10];
    float* ws = (float*)d_ws;

    nn_kernel<<<3648, 256, 0, stream>>>(pred, full, partial, plane_n,
                                        plane_off, pred_n, gt_n, ws);
    pass2_kernel<<<224, 256, 0, stream>>>(pred, full, partial, ws);
    final_kernel<<<1, 256, 0, stream>>>(ws, confs, diff, (float*)d_out);
}